// Round 9
// baseline (148.955 us; speedup 1.0000x reference)
//
#include <hip/hip_runtime.h>
#include <math.h>

#define NB 8
#define NQ 256
#define NK 256
#define DIN 10
#define FDIM 64
#define HIDDEN 256
#define NH 8
#define ROWS_PER_BLK 2

#define FSTRIDE 64    // shorts per feat row; XOR-swizzled 8-short col-blocks
#define HSTRIDE 264   // shorts per h row (256 + 8 pad) -> 528 B

typedef float f32x4 __attribute__((ext_vector_type(4)));
typedef float f32x2 __attribute__((ext_vector_type(2)));
typedef short bf16x8 __attribute__((ext_vector_type(8)));

__device__ __forceinline__ short f2bf(float f) {
    return (short)((__float_as_uint(f) + 0x8000u) >> 16);
}
// pack two floats -> two bf16 in ONE instr (RTNE). a -> low half, b -> high.
__device__ __forceinline__ unsigned cvtpk(float a, float b) {
    unsigned r;
    asm("v_cvt_pk_bf16_f32 %0, %1, %2" : "=v"(r) : "v"(a), "v"(b));
    return r;
}
__device__ __forceinline__ float rcpf(float x) { return __builtin_amdgcn_rcpf(x); }
__device__ __forceinline__ float ex2f(float x) { return __builtin_amdgcn_exp2f(x); }
__device__ __forceinline__ float sqtf(float x) { return __builtin_amdgcn_sqrtf(x); }

__device__ __forceinline__ void four4(float x, float* dst) {
    float s1 = __sinf(x), c1 = __cosf(x);
    float s2 = 2.f * s1 * c1, c2 = 1.f - 2.f * s1 * s1;
    float s4 = 2.f * s2 * c2, c4 = 1.f - 2.f * s2 * s2;
    float s8 = 2.f * s4 * c4, c8 = 1.f - 2.f * s4 * s4;
    dst[0] = s1; dst[1] = s2; dst[2] = s4; dst[3] = s8;
    dst[4] = c1; dst[5] = c2; dst[6] = c4; dst[7] = c8;
}
__device__ __forceinline__ void four2(float x, float* dst) {
    float s1 = __sinf(x), c1 = __cosf(x);
    dst[0] = s1; dst[1] = 2.f * s1 * c1;
    dst[2] = c1; dst[3] = 1.f - 2.f * s1 * s1;
}

// r9 = r5's proven chunk body + per-chunk feat ping-pong -> LDS 50176 B
//      -> 3 blocks/CU (r8 showed co-resident independent blocks, not
//      barrier count, is the binding resource: 2 blk 51.2us > 1 blk 56.5us).
//   feat_s[256] replaced by feat2[2][64]: chunk c+1's features are computed
//   during chunk c's pre-bar1 region by the 2 waves whose cached k-rows
//   cover that 64-pair range ((p>>6)==(c+1)&3, wave-uniform; k regs valid).
//   Streamed r7-proven form (8 feats at a time -> no spill at 64 VGPR).
//   Hazards: feat2[(c+1)&1] writes (body c, pre-bar1) vs G1(c+1) reads
//     (post bar2(c)): RAW sealed. G1(c) reads feat2[c&1] (pre-bar1(c)) vs
//     next writes to that buffer (body c+1): WAR sealed by bar1+bar2(c).
//   h_s scheme verbatim r5: G1;silu;feat;bar1;h-write;bar2;G2(c).
//   Serial per-row feature phase + its barrier deleted (8 bar/row).
//   ROWS_PER_BLK=2 -> grid 1024 (>=768 needed for 3 residents/CU).
//   amdgpu_waves_per_eu(6,8): VGPR target <=85 for the 6-wave/SIMD tier.
// Scale folds unchanged: W1,b1 x -log2(e); W2 x -ln(2).
__global__ __attribute__((amdgpu_flat_work_group_size(512, 512),
                          amdgpu_waves_per_eu(6, 8)))
void relfeat_mfma_kernel(
    const float* __restrict__ q, const float* __restrict__ k,
    const float* __restrict__ W1, const float* __restrict__ b1,
    const float* __restrict__ W2, const float* __restrict__ b2,
    float* __restrict__ out)
{
    __shared__ __align__(16) short feat2[2][64 * FSTRIDE];  // 16384 B
    __shared__ __align__(16) short h_s[64 * HSTRIDE];       // 33792 B

    const int t = threadIdx.x;          // 0..511
    const int wave = t >> 6;            // 0..7
    const int lane15 = t & 15;
    const int quad = (t >> 4) & 3;
    const int p = t & 255;              // pair id owned by this thread
    const int half = t >> 8;            // 0/1: which half of features
    const int b = blockIdx.x >> 7;
    const int i0 = (blockIdx.x & 127) * ROWS_PER_BLK;

    // ---- k-row for pair j = p: block-invariant, cache in regs ----
    const float* kp = k + ((size_t)b * NK + p) * DIN;
    const float k0 = kp[0], k3 = kp[3], k4 = kp[4], k5 = kp[5], k6 = kp[6],
                k7 = kp[7], k8 = kp[8];
    const float k_speed = sqtf(k5 * k5 + k6 * k6);   // row-invariant

    // ---- W2 fragments in regs (GEMM2 B-operand), scaled by -ln2 ----
    bf16x8 w2f[8];
    if (wave < 4) {
#pragma unroll
        for (int ks = 0; ks < 8; ++ks) {
            const float* wp = W2 + (size_t)(ks * 32 + quad * 8) * NH + (lane15 & 7);
            bf16x8 v;
#pragma unroll
            for (int e = 0; e < 8; ++e)
                v[e] = f2bf(-0.69314718f * wp[(size_t)e * NH]);
            w2f[ks] = v;
        }
    }

    // ---- W1 fragments (A operand), scaled by -log2e ----
    const int n0 = wave * 32;
    bf16x8 w1f[2][2];
#pragma unroll
    for (int nt = 0; nt < 2; ++nt)
#pragma unroll
        for (int ks = 0; ks < 2; ++ks) {
            const float* wp = W1 + (size_t)(ks * 32 + quad * 8) * HIDDEN
                              + (n0 + nt * 16 + lane15);
            bf16x8 v;
#pragma unroll
            for (int e = 0; e < 8; ++e)
                v[e] = f2bf(-1.44269504f * wp[(size_t)e * HIDDEN]);
            w1f[nt][ks] = v;
        }
    // bias fragment (MFMA C-in at ks=0), scaled by -log2e
    f32x4 b1c[2];
#pragma unroll
    for (int nt = 0; nt < 2; ++nt) {
        float4 bb = *(const float4*)&b1[n0 + nt * 16 + quad * 4];
        b1c[nt] = (f32x4){-1.44269504f * bb.x, -1.44269504f * bb.y,
                          -1.44269504f * bb.z, -1.44269504f * bb.w};
    }
    const float b2v = (lane15 < NH) ? b2[lane15] : 0.f;
    // G2 output pointer base (valid only when lane15 < NH; never deref'd else)
    float* const outp = out + ((size_t)b * NH + (lane15 & 7)) * NQ * NK
                        + wave * 16 + quad * 4;

    const int sw = p & 7;        // feature-store swizzle (lp&7 == p&7)
    const int swr = lane15 & 7;  // feat B-frag read swizzle
    const int lp = p & 63;       // local pair row inside a chunk buffer
    const f32x2 one2 = {1.f, 1.f};

    // ---- streamed 32-feature half for pair p, row irow -> feat2[wbuf] ----
    // r7-proven low-pressure form: compute 8 -> cvtpk -> ds_write, repeat.
    auto feat_task = [&](int irow, int wbuf) {
        const float* qp = q + ((size_t)b * NQ + irow) * DIN;
        const float q0 = qp[0], q3 = qp[3], q4 = qp[4], q5 = qp[5],
                    q6 = qp[6], q7 = qp[7], q8 = qp[8];
        const float dpx = k3 - q3, dpy = k4 - q4;
        const float dvx = k5 - q5, dvy = k6 - q6;
        const float dist = sqtf(dpx * dpx + dpy * dpy + 1e-6f);
        float f8[8];
        auto fstore = [&](int c8) {
            uint4 v;
            v.x = cvtpk(f8[0], f8[1]);
            v.y = cvtpk(f8[2], f8[3]);
            v.z = cvtpk(f8[4], f8[5]);
            v.w = cvtpk(f8[6], f8[7]);
            *(uint4*)&feat2[wbuf][lp * FSTRIDE + ((c8 ^ sw) * 8)] = v;
        };
        if (half == 0) {
            // c8 0: dist^(1,2,4,8); keep s/c for the c8=6 reuse
            four4(dist, f8);
            const float ds1 = f8[0], ds2 = f8[1], dc1 = f8[4], dc2 = f8[5];
            fstore(0);
            four4(rcpf(dist + 0.1f), f8);
            fstore(1);
            // c8 6: ttca | dist-reuse
            const float dd = dpx * dvx + dpy * dvy;
            const float ss = dvx * dvx + dvy * dvy;
            // tanh(relu(z)) = 1 - 2/(1 + 2^(2*log2e*z)), z >= 0
            const float z = fmaxf(0.f, -dd * rcpf(ss + 1e-6f));
            const float ttca = 1.f - 2.f * rcpf(1.f + ex2f(2.88539008f * z));
            four2(ttca, f8);
            f8[4] = ds1; f8[5] = ds2; f8[6] = dc1; f8[7] = dc2;
            fstore(6);
            // c8 7: same_team consts | delta_speed
            const bool st = (q0 == k0);
            f8[0] = st ? 0.84147098f : 0.f;      // sin(1)/sin(0)
            f8[1] = st ? 0.90929743f : 0.f;      // sin(2)/sin(0)
            f8[2] = st ? 0.54030231f : 1.f;      // cos(1)/cos(0)
            f8[3] = st ? -0.41614684f : 1.f;     // cos(2)/cos(0)
            four2(k_speed - sqtf(q5 * q5 + q6 * q6), f8 + 4);
            fstore(7);
        } else {
            // c8 2,3: ata | aspect
            const float inv_d2 = rcpf(dist + 1e-6f);
            const float bx = dpx * inv_d2, by = dpy * inv_d2;
            four4(bx * q7 + by * q8, f8); fstore(2);
            four4(bx * k7 + by * k8, f8); fstore(3);
            // c8 4: dpx|dpy ; c8 5: dvx|dvy
            four2(dpx, f8); four2(dpy, f8 + 4); fstore(4);
            four2(dvx, f8); four2(dvy, f8 + 4); fstore(5);
        }
    };

    // ---- prologue: features(row i0, chunk 0) into feat2[0] ----
    if ((p >> 6) == 0)
        feat_task(i0, 0);
    __syncthreads();

    // ================= row loop: 2 query rows =================
#pragma unroll 1
    for (int row = 0; row < ROWS_PER_BLK; ++row) {
        const int i = i0 + row;

        // ---- 4 chunks of 64 pairs (r5 barrier scheme: bar1 + bar2) ----
#pragma unroll 1
        for (int c = 0; c < 4; ++c) {
            const int p0 = c * 64;
            const int rb = c & 1;            // feat read buffer

            // GEMM1': bias rides as C-in on the ks=0 MFMAs
            f32x4 acc[2][4];
#pragma unroll
            for (int mt = 0; mt < 4; ++mt) {
                const int lp2 = mt * 16 + lane15;
                const bf16x8 fb = *(const bf16x8*)
                    &feat2[rb][lp2 * FSTRIDE + ((quad ^ swr) * 8)];
                acc[0][mt] = __builtin_amdgcn_mfma_f32_16x16x32_bf16(
                    w1f[0][0], fb, b1c[0], 0, 0, 0);
                acc[1][mt] = __builtin_amdgcn_mfma_f32_16x16x32_bf16(
                    w1f[1][0], fb, b1c[1], 0, 0, 0);
            }
#pragma unroll
            for (int mt = 0; mt < 4; ++mt) {
                const int lp2 = mt * 16 + lane15;
                const bf16x8 fb = *(const bf16x8*)
                    &feat2[rb][lp2 * FSTRIDE + (((4 + quad) ^ swr) * 8)];
#pragma unroll
                for (int nt = 0; nt < 2; ++nt)
                    acc[nt][mt] = __builtin_amdgcn_mfma_f32_16x16x32_bf16(
                        w1f[nt][1], fb, acc[nt][mt], 0, 0, 0);
            }

            // silu-COMPUTE into regs (packed-f32 add/mul)
            uint2 pk[2][4];
#pragma unroll
            for (int nt = 0; nt < 2; ++nt)
#pragma unroll
                for (int mt = 0; mt < 4; ++mt) {
                    const f32x4 a = acc[nt][mt];     // = -log2e * preact
                    const f32x2 a01 = {a[0], a[1]}, a23 = {a[2], a[3]};
                    const f32x2 e01 = {ex2f(a[0]), ex2f(a[1])};
                    const f32x2 e23 = {ex2f(a[2]), ex2f(a[3])};
                    const f32x2 t01 = e01 + one2;    // v_pk_add_f32
                    const f32x2 t23 = e23 + one2;
                    const f32x2 r01 = {rcpf(t01[0]), rcpf(t01[1])};
                    const f32x2 r23 = {rcpf(t23[0]), rcpf(t23[1])};
                    const f32x2 s01 = a01 * r01;     // v_pk_mul_f32
                    const f32x2 s23 = a23 * r23;     // = -1.4427*silu
                    pk[nt][mt].x = cvtpk(s01[0], s01[1]);
                    pk[nt][mt].y = cvtpk(s23[0], s23[1]);
                }

            // features for chunk c+1 (next row's c0 when c==3), by the
            // 2 waves owning that pair range; wave-uniform predicate.
            {
                const int tc = (c + 1) & 3;
                const bool last = (row == ROWS_PER_BLK - 1) && (c == 3);
                if ((p >> 6) == tc && !last)
                    feat_task(i + (c == 3), (c + 1) & 1);
            }

            __syncthreads();  // bar1: h_s(prev chunk) fully consumed

            // only the 8 ds_write_b64 live between the barriers
#pragma unroll
            for (int nt = 0; nt < 2; ++nt)
#pragma unroll
                for (int mt = 0; mt < 4; ++mt) {
                    const int pair = mt * 16 + lane15;
                    const int hbase = n0 + nt * 16 + quad * 4;
                    *(uint2*)&h_s[pair * HSTRIDE + hbase] = pk[nt][mt];
                }
            __syncthreads();  // bar2: h_s(c) ready; feat2[(c+1)&1] sealed

            // GEMM2: waves 0-3, one 16-pair M-tile each; K=256; W2 in regs
            if (wave < 4) {
                const int pw = wave * 16;
                f32x4 acc2 = (f32x4){b2v, b2v, b2v, b2v};
#pragma unroll
                for (int ks = 0; ks < 8; ++ks) {
                    const bf16x8 ha = *(const bf16x8*)&h_s[(pw + lane15) * HSTRIDE
                                                            + ks * 32 + quad * 8];
                    acc2 = __builtin_amdgcn_mfma_f32_16x16x32_bf16(ha, w2f[ks], acc2, 0, 0, 0);
                }
                if (lane15 < NH) {
                    float* op = outp + (size_t)i * NK + p0;
                    *(float4*)op = make_float4(acc2[0], acc2[1], acc2[2], acc2[3]);
                }
            }
            // no end barrier: next chunk's G1 reads feat2[(c+1)&1] (sealed
            // by bar2) and h_s WAR is guarded by next chunk's bar1.
        }
    }
}

extern "C" void kernel_launch(void* const* d_in, const int* in_sizes, int n_in,
                              void* d_out, int out_size, void* d_ws, size_t ws_size,
                              hipStream_t stream) {
    const float* q  = (const float*)d_in[0];
    const float* k  = (const float*)d_in[1];
    const float* W1 = (const float*)d_in[2];
    const float* b1 = (const float*)d_in[3];
    const float* W2 = (const float*)d_in[4];
    const float* b2 = (const float*)d_in[5];
    float* out = (float*)d_out;

    dim3 grid(NB * NQ / ROWS_PER_BLK);  // 1024 blocks; 3 resident/CU (LDS)
    dim3 block(512);                    // 8 waves
    relfeat_mfma_kernel<<<grid, block, 0, stream>>>(q, k, W1, b1, W2, b2, out);
}

// Round 10
// 117.306 us; speedup vs baseline: 1.2698x; 1.2698x over previous
//
#include <hip/hip_runtime.h>
#include <math.h>

#define NB 8
#define NQ 256
#define NK 256
#define DIN 10
#define FDIM 64
#define HIDDEN 256
#define NH 8
#define ROWS_PER_BLK 2

#define FSTRIDE 64    // shorts per feat row; XOR-swizzled 8-short col-blocks
#define HSTRIDE 264   // shorts per h row (256 + 8 pad) -> 528 B

typedef float f32x4 __attribute__((ext_vector_type(4)));
typedef float f32x2 __attribute__((ext_vector_type(2)));
typedef short bf16x8 __attribute__((ext_vector_type(8)));

__device__ __forceinline__ short f2bf(float f) {
    return (short)((__float_as_uint(f) + 0x8000u) >> 16);
}
// pack two floats -> two bf16 in ONE instr (RTNE). a -> low half, b -> high.
__device__ __forceinline__ unsigned cvtpk(float a, float b) {
    unsigned r;
    asm("v_cvt_pk_bf16_f32 %0, %1, %2" : "=v"(r) : "v"(a), "v"(b));
    return r;
}
__device__ __forceinline__ float rcpf(float x) { return __builtin_amdgcn_rcpf(x); }
__device__ __forceinline__ float ex2f(float x) { return __builtin_amdgcn_exp2f(x); }
__device__ __forceinline__ float sqtf(float x) { return __builtin_amdgcn_sqrtf(x); }

__device__ __forceinline__ void four4(float x, float* dst) {
    float s1 = __sinf(x), c1 = __cosf(x);
    float s2 = 2.f * s1 * c1, c2 = 1.f - 2.f * s1 * s1;
    float s4 = 2.f * s2 * c2, c4 = 1.f - 2.f * s2 * s2;
    float s8 = 2.f * s4 * c4, c8 = 1.f - 2.f * s4 * s4;
    dst[0] = s1; dst[1] = s2; dst[2] = s4; dst[3] = s8;
    dst[4] = c1; dst[5] = c2; dst[6] = c4; dst[7] = c8;
}
__device__ __forceinline__ void four2(float x, float* dst) {
    float s1 = __sinf(x), c1 = __cosf(x);
    dst[0] = s1; dst[1] = 2.f * s1 * c1;
    dst[2] = c1; dst[3] = 1.f - 2.f * s1 * s1;
}

// r10 = r9 structure (correctness-proven) with the ONE variable changed:
//   register-budget config restored to __launch_bounds__(512, 4) — the
//   setting that compiled this same streamed-feature body to VGPR=64 with
//   zero spill in r5/r7. r9's amdgpu_waves_per_eu(6,8) drove the allocator
//   to VGPR=40 + ~100MB scratch traffic (WRITE 119MB); that attribute is
//   the failure, not the structure.
// Structure recap (clean test of the 3-blocks/CU de-phasing hypothesis;
// r8 measured 1blk=56.5 < 2blk=51.2, mechanism: co-resident independent
// blocks fill each other's barrier-drain windows):
//   feat_s[256] -> feat2[2][64] ping-pong (16384 B); LDS total 50176 B ->
//   3 blocks/CU resident. Chunk c+1's features computed during chunk c's
//   pre-bar1 region by the 2 waves owning that pair range (wave-uniform
//   predicate, k-rows already in regs, r7-proven streamed form).
//   Hazards: feat2[(c+1)&1] writes pre-bar1(c) vs G1(c+1) reads post-
//     bar2(c): RAW sealed. G1(c) reads feat2[c&1] pre-bar1(c) vs writes in
//     body c+1 (post-bar2(c)): WAR sealed.
//   h_s scheme verbatim r5: G1;silu;feat;bar1;h-write;bar2;G2.
//   ROWS_PER_BLK=2 -> grid 1024 (>=768 needed for 3 residents/CU).
// Scale folds unchanged: W1,b1 x -log2(e); W2 x -ln(2).
__global__ __launch_bounds__(512, 4) void relfeat_mfma_kernel(
    const float* __restrict__ q, const float* __restrict__ k,
    const float* __restrict__ W1, const float* __restrict__ b1,
    const float* __restrict__ W2, const float* __restrict__ b2,
    float* __restrict__ out)
{
    __shared__ __align__(16) short feat2[2][64 * FSTRIDE];  // 16384 B
    __shared__ __align__(16) short h_s[64 * HSTRIDE];       // 33792 B

    const int t = threadIdx.x;          // 0..511
    const int wave = t >> 6;            // 0..7
    const int lane15 = t & 15;
    const int quad = (t >> 4) & 3;
    const int p = t & 255;              // pair id owned by this thread
    const int half = t >> 8;            // 0/1: which half of features
    const int b = blockIdx.x >> 7;
    const int i0 = (blockIdx.x & 127) * ROWS_PER_BLK;

    // ---- k-row for pair j = p: block-invariant, cache in regs ----
    const float* kp = k + ((size_t)b * NK + p) * DIN;
    const float k0 = kp[0], k3 = kp[3], k4 = kp[4], k5 = kp[5], k6 = kp[6],
                k7 = kp[7], k8 = kp[8];
    const float k_speed = sqtf(k5 * k5 + k6 * k6);   // row-invariant

    // ---- W2 fragments in regs (GEMM2 B-operand), scaled by -ln2 ----
    bf16x8 w2f[8];
    if (wave < 4) {
#pragma unroll
        for (int ks = 0; ks < 8; ++ks) {
            const float* wp = W2 + (size_t)(ks * 32 + quad * 8) * NH + (lane15 & 7);
            bf16x8 v;
#pragma unroll
            for (int e = 0; e < 8; ++e)
                v[e] = f2bf(-0.69314718f * wp[(size_t)e * NH]);
            w2f[ks] = v;
        }
    }

    // ---- W1 fragments (A operand), scaled by -log2e ----
    const int n0 = wave * 32;
    bf16x8 w1f[2][2];
#pragma unroll
    for (int nt = 0; nt < 2; ++nt)
#pragma unroll
        for (int ks = 0; ks < 2; ++ks) {
            const float* wp = W1 + (size_t)(ks * 32 + quad * 8) * HIDDEN
                              + (n0 + nt * 16 + lane15);
            bf16x8 v;
#pragma unroll
            for (int e = 0; e < 8; ++e)
                v[e] = f2bf(-1.44269504f * wp[(size_t)e * HIDDEN]);
            w1f[nt][ks] = v;
        }
    // bias fragment (MFMA C-in at ks=0), scaled by -log2e
    f32x4 b1c[2];
#pragma unroll
    for (int nt = 0; nt < 2; ++nt) {
        float4 bb = *(const float4*)&b1[n0 + nt * 16 + quad * 4];
        b1c[nt] = (f32x4){-1.44269504f * bb.x, -1.44269504f * bb.y,
                          -1.44269504f * bb.z, -1.44269504f * bb.w};
    }
    const float b2v = (lane15 < NH) ? b2[lane15] : 0.f;
    // G2 output pointer base (valid only when lane15 < NH; never deref'd else)
    float* const outp = out + ((size_t)b * NH + (lane15 & 7)) * NQ * NK
                        + wave * 16 + quad * 4;

    const int sw = p & 7;        // feature-store swizzle (lp&7 == p&7)
    const int swr = lane15 & 7;  // feat B-frag read swizzle
    const int lp = p & 63;       // local pair row inside a chunk buffer
    const f32x2 one2 = {1.f, 1.f};

    // ---- streamed 32-feature half for pair p, row irow -> feat2[wbuf] ----
    // r7-proven low-pressure form: compute 8 -> cvtpk -> ds_write, repeat.
    auto feat_task = [&](int irow, int wbuf) {
        const float* qp = q + ((size_t)b * NQ + irow) * DIN;
        const float q0 = qp[0], q3 = qp[3], q4 = qp[4], q5 = qp[5],
                    q6 = qp[6], q7 = qp[7], q8 = qp[8];
        const float dpx = k3 - q3, dpy = k4 - q4;
        const float dvx = k5 - q5, dvy = k6 - q6;
        const float dist = sqtf(dpx * dpx + dpy * dpy + 1e-6f);
        float f8[8];
        auto fstore = [&](int c8) {
            uint4 v;
            v.x = cvtpk(f8[0], f8[1]);
            v.y = cvtpk(f8[2], f8[3]);
            v.z = cvtpk(f8[4], f8[5]);
            v.w = cvtpk(f8[6], f8[7]);
            *(uint4*)&feat2[wbuf][lp * FSTRIDE + ((c8 ^ sw) * 8)] = v;
        };
        if (half == 0) {
            // c8 0: dist^(1,2,4,8); keep s/c for the c8=6 reuse
            four4(dist, f8);
            const float ds1 = f8[0], ds2 = f8[1], dc1 = f8[4], dc2 = f8[5];
            fstore(0);
            four4(rcpf(dist + 0.1f), f8);
            fstore(1);
            // c8 6: ttca | dist-reuse
            const float dd = dpx * dvx + dpy * dvy;
            const float ss = dvx * dvx + dvy * dvy;
            // tanh(relu(z)) = 1 - 2/(1 + 2^(2*log2e*z)), z >= 0
            const float z = fmaxf(0.f, -dd * rcpf(ss + 1e-6f));
            const float ttca = 1.f - 2.f * rcpf(1.f + ex2f(2.88539008f * z));
            four2(ttca, f8);
            f8[4] = ds1; f8[5] = ds2; f8[6] = dc1; f8[7] = dc2;
            fstore(6);
            // c8 7: same_team consts | delta_speed
            const bool st = (q0 == k0);
            f8[0] = st ? 0.84147098f : 0.f;      // sin(1)/sin(0)
            f8[1] = st ? 0.90929743f : 0.f;      // sin(2)/sin(0)
            f8[2] = st ? 0.54030231f : 1.f;      // cos(1)/cos(0)
            f8[3] = st ? -0.41614684f : 1.f;     // cos(2)/cos(0)
            four2(k_speed - sqtf(q5 * q5 + q6 * q6), f8 + 4);
            fstore(7);
        } else {
            // c8 2,3: ata | aspect
            const float inv_d2 = rcpf(dist + 1e-6f);
            const float bx = dpx * inv_d2, by = dpy * inv_d2;
            four4(bx * q7 + by * q8, f8); fstore(2);
            four4(bx * k7 + by * k8, f8); fstore(3);
            // c8 4: dpx|dpy ; c8 5: dvx|dvy
            four2(dpx, f8); four2(dpy, f8 + 4); fstore(4);
            four2(dvx, f8); four2(dvy, f8 + 4); fstore(5);
        }
    };

    // ---- prologue: features(row i0, chunk 0) into feat2[0] ----
    if ((p >> 6) == 0)
        feat_task(i0, 0);
    __syncthreads();

    // ================= row loop: 2 query rows =================
#pragma unroll 1
    for (int row = 0; row < ROWS_PER_BLK; ++row) {
        const int i = i0 + row;

        // ---- 4 chunks of 64 pairs (r5 barrier scheme: bar1 + bar2) ----
#pragma unroll 1
        for (int c = 0; c < 4; ++c) {
            const int p0 = c * 64;
            const int rb = c & 1;            // feat read buffer

            // GEMM1': bias rides as C-in on the ks=0 MFMAs
            f32x4 acc[2][4];
#pragma unroll
            for (int mt = 0; mt < 4; ++mt) {
                const int lp2 = mt * 16 + lane15;
                const bf16x8 fb = *(const bf16x8*)
                    &feat2[rb][lp2 * FSTRIDE + ((quad ^ swr) * 8)];
                acc[0][mt] = __builtin_amdgcn_mfma_f32_16x16x32_bf16(
                    w1f[0][0], fb, b1c[0], 0, 0, 0);
                acc[1][mt] = __builtin_amdgcn_mfma_f32_16x16x32_bf16(
                    w1f[1][0], fb, b1c[1], 0, 0, 0);
            }
#pragma unroll
            for (int mt = 0; mt < 4; ++mt) {
                const int lp2 = mt * 16 + lane15;
                const bf16x8 fb = *(const bf16x8*)
                    &feat2[rb][lp2 * FSTRIDE + (((4 + quad) ^ swr) * 8)];
#pragma unroll
                for (int nt = 0; nt < 2; ++nt)
                    acc[nt][mt] = __builtin_amdgcn_mfma_f32_16x16x32_bf16(
                        w1f[nt][1], fb, acc[nt][mt], 0, 0, 0);
            }

            // silu-COMPUTE into regs (packed-f32 add/mul)
            uint2 pk[2][4];
#pragma unroll
            for (int nt = 0; nt < 2; ++nt)
#pragma unroll
                for (int mt = 0; mt < 4; ++mt) {
                    const f32x4 a = acc[nt][mt];     // = -log2e * preact
                    const f32x2 a01 = {a[0], a[1]}, a23 = {a[2], a[3]};
                    const f32x2 e01 = {ex2f(a[0]), ex2f(a[1])};
                    const f32x2 e23 = {ex2f(a[2]), ex2f(a[3])};
                    const f32x2 t01 = e01 + one2;    // v_pk_add_f32
                    const f32x2 t23 = e23 + one2;
                    const f32x2 r01 = {rcpf(t01[0]), rcpf(t01[1])};
                    const f32x2 r23 = {rcpf(t23[0]), rcpf(t23[1])};
                    const f32x2 s01 = a01 * r01;     // v_pk_mul_f32
                    const f32x2 s23 = a23 * r23;     // = -1.4427*silu
                    pk[nt][mt].x = cvtpk(s01[0], s01[1]);
                    pk[nt][mt].y = cvtpk(s23[0], s23[1]);
                }

            // features for chunk c+1 (next row's c0 when c==3), by the
            // 2 waves owning that pair range; wave-uniform predicate.
            {
                const int tc = (c + 1) & 3;
                const bool last = (row == ROWS_PER_BLK - 1) && (c == 3);
                if ((p >> 6) == tc && !last)
                    feat_task(i + (c == 3), (c + 1) & 1);
            }

            __syncthreads();  // bar1: h_s(prev chunk) fully consumed

            // only the 8 ds_write_b64 live between the barriers
#pragma unroll
            for (int nt = 0; nt < 2; ++nt)
#pragma unroll
                for (int mt = 0; mt < 4; ++mt) {
                    const int pair = mt * 16 + lane15;
                    const int hbase = n0 + nt * 16 + quad * 4;
                    *(uint2*)&h_s[pair * HSTRIDE + hbase] = pk[nt][mt];
                }
            __syncthreads();  // bar2: h_s(c) ready; feat2[(c+1)&1] sealed

            // GEMM2: waves 0-3, one 16-pair M-tile each; K=256; W2 in regs
            if (wave < 4) {
                const int pw = wave * 16;
                f32x4 acc2 = (f32x4){b2v, b2v, b2v, b2v};
#pragma unroll
                for (int ks = 0; ks < 8; ++ks) {
                    const bf16x8 ha = *(const bf16x8*)&h_s[(pw + lane15) * HSTRIDE
                                                            + ks * 32 + quad * 8];
                    acc2 = __builtin_amdgcn_mfma_f32_16x16x32_bf16(ha, w2f[ks], acc2, 0, 0, 0);
                }
                if (lane15 < NH) {
                    float* op = outp + (size_t)i * NK + p0;
                    *(float4*)op = make_float4(acc2[0], acc2[1], acc2[2], acc2[3]);
                }
            }
            // no end barrier: next chunk's G1 reads feat2[(c+1)&1] (sealed
            // by bar2) and h_s WAR is guarded by next chunk's bar1.
        }
    }
}

extern "C" void kernel_launch(void* const* d_in, const int* in_sizes, int n_in,
                              void* d_out, int out_size, void* d_ws, size_t ws_size,
                              hipStream_t stream) {
    const float* q  = (const float*)d_in[0];
    const float* k  = (const float*)d_in[1];
    const float* W1 = (const float*)d_in[2];
    const float* b1 = (const float*)d_in[3];
    const float* W2 = (const float*)d_in[4];
    const float* b2 = (const float*)d_in[5];
    float* out = (float*)d_out;

    dim3 grid(NB * NQ / ROWS_PER_BLK);  // 1024 blocks; 3 resident/CU (LDS)
    dim3 block(512);                    // 8 waves
    relfeat_mfma_kernel<<<grid, block, 0, stream>>>(q, k, W1, b1, W2, b2, out);
}

// Round 11
// 106.949 us; speedup vs baseline: 1.3928x; 1.0968x over previous
//
#include <hip/hip_runtime.h>
#include <math.h>

#define NB 8
#define NQ 256
#define NK 256
#define DIN 10
#define FDIM 64
#define HIDDEN 256
#define NH 8
#define ROWS_PER_BLK 4

#define FSTRIDE 64    // shorts per feat row; XOR-swizzled 8-short col-blocks
#define HSTRIDE 264   // shorts per h row (256 + 8 pad) -> 528 B

typedef float f32x4 __attribute__((ext_vector_type(4)));
typedef float f32x2 __attribute__((ext_vector_type(2)));
typedef short bf16x8 __attribute__((ext_vector_type(8)));

__device__ __forceinline__ short f2bf(float f) {
    return (short)((__float_as_uint(f) + 0x8000u) >> 16);
}
// pack two floats -> two bf16 in ONE instr (RTNE). a -> low half, b -> high.
__device__ __forceinline__ unsigned cvtpk(float a, float b) {
    unsigned r;
    asm("v_cvt_pk_bf16_f32 %0, %1, %2" : "=v"(r) : "v"(a), "v"(b));
    return r;
}
__device__ __forceinline__ float rcpf(float x) { return __builtin_amdgcn_rcpf(x); }
__device__ __forceinline__ float ex2f(float x) { return __builtin_amdgcn_exp2f(x); }
__device__ __forceinline__ float sqtf(float x) { return __builtin_amdgcn_sqrtf(x); }

__device__ __forceinline__ void four4(float x, float* dst) {
    float s1 = __sinf(x), c1 = __cosf(x);
    float s2 = 2.f * s1 * c1, c2 = 1.f - 2.f * s1 * s1;
    float s4 = 2.f * s2 * c2, c4 = 1.f - 2.f * s2 * s2;
    float s8 = 2.f * s4 * c4, c8 = 1.f - 2.f * s4 * s4;
    dst[0] = s1; dst[1] = s2; dst[2] = s4; dst[3] = s8;
    dst[4] = c1; dst[5] = c2; dst[6] = c4; dst[7] = c8;
}
__device__ __forceinline__ void four2(float x, float* dst) {
    float s1 = __sinf(x), c1 = __cosf(x);
    dst[0] = s1; dst[1] = 2.f * s1 * c1;
    dst[2] = c1; dst[3] = 1.f - 2.f * s1 * s1;
}

// r11 = EXACT REVERT to r5, the session's best harness-verified kernel
// (51.2us dispatch / 107.7us bench). Ledger that justifies the revert:
//   r1 occupancy x2 -> 0%; r2 issue -12% -> -5%; r3 G2-pipeline -> spill;
//   r8 1-barrier ping-pong @1blk/CU -> -10%; r7 feature-overlap -> 0%;
//   r10 3-blk/CU de-phasing (clean, no spill) -> -15%; r9 waves_per_eu(6,8)
//   -> VGPR 40 + 100MB scratch. Every structural rearrangement was
//   neutral-to-negative once spill-free; all real gains were instruction
//   trims on this lineage. r5 is the measured local optimum: no pipe >50%,
//   trans within ~25% of chip floor, 7 structural attacks failed.
// r5 = r2 shape (512 thr, 2 blk/CU) + spill-free instruction trims:
//   - bias as MFMA C-in at ks=0; packed-f32 silu (v_pk_add/mul);
//   - raw rcp/sqrt + exp2-form tanh in features; G2 out-pointer hoisted.
// Scale folds: W1,b1 pre-scaled by -log2(e); W2 by -ln(2).
__global__ __launch_bounds__(512, 4) void relfeat_mfma_kernel(
    const float* __restrict__ q, const float* __restrict__ k,
    const float* __restrict__ W1, const float* __restrict__ b1,
    const float* __restrict__ W2, const float* __restrict__ b2,
    float* __restrict__ out)
{
    __shared__ __align__(16) short feat_s[NK * FSTRIDE];   // 32768 B
    __shared__ __align__(16) short h_s[64 * HSTRIDE];      // 33792 B

    const int t = threadIdx.x;          // 0..511
    const int wave = t >> 6;            // 0..7
    const int lane15 = t & 15;
    const int quad = (t >> 4) & 3;
    const int p = t & 255;              // pair id for features / staging
    const int half = t >> 8;            // 0/1: which half of features
    const int b = blockIdx.x >> 6;
    const int i0 = (blockIdx.x & 63) * ROWS_PER_BLK;

    // ---- k-row for pair j = p: block-invariant, cache in regs ----
    const float* kp = k + ((size_t)b * NK + p) * DIN;
    const float k0 = kp[0], k3 = kp[3], k4 = kp[4], k5 = kp[5], k6 = kp[6],
                k7 = kp[7], k8 = kp[8];
    const float k_speed = sqtf(k5 * k5 + k6 * k6);   // row-invariant

    // ---- W2 fragments in regs (GEMM2 B-operand), scaled by -ln2 ----
    bf16x8 w2f[8];
    if (wave < 4) {
#pragma unroll
        for (int ks = 0; ks < 8; ++ks) {
            const float* wp = W2 + (size_t)(ks * 32 + quad * 8) * NH + (lane15 & 7);
            bf16x8 v;
#pragma unroll
            for (int e = 0; e < 8; ++e)
                v[e] = f2bf(-0.69314718f * wp[(size_t)e * NH]);
            w2f[ks] = v;
        }
    }

    // ---- W1 fragments (A operand), scaled by -log2e ----
    const int n0 = wave * 32;
    bf16x8 w1f[2][2];
#pragma unroll
    for (int nt = 0; nt < 2; ++nt)
#pragma unroll
        for (int ks = 0; ks < 2; ++ks) {
            const float* wp = W1 + (size_t)(ks * 32 + quad * 8) * HIDDEN
                              + (n0 + nt * 16 + lane15);
            bf16x8 v;
#pragma unroll
            for (int e = 0; e < 8; ++e)
                v[e] = f2bf(-1.44269504f * wp[(size_t)e * HIDDEN]);
            w1f[nt][ks] = v;
        }
    // bias fragment (MFMA C-in at ks=0), scaled by -log2e
    f32x4 b1c[2];
#pragma unroll
    for (int nt = 0; nt < 2; ++nt) {
        float4 bb = *(const float4*)&b1[n0 + nt * 16 + quad * 4];
        b1c[nt] = (f32x4){-1.44269504f * bb.x, -1.44269504f * bb.y,
                          -1.44269504f * bb.z, -1.44269504f * bb.w};
    }
    const float b2v = (lane15 < NH) ? b2[lane15] : 0.f;
    // G2 output pointer base (valid only when lane15 < NH; never deref'd else)
    float* const outp = out + ((size_t)b * NH + (lane15 & 7)) * NQ * NK
                        + wave * 16 + quad * 4;

    const int sw = p & 7;        // feature-store swizzle
    const int swr = lane15 & 7;  // feat B-frag read swizzle
    const f32x2 one2 = {1.f, 1.f};

    // ================= row loop: 4 query rows =================
#pragma unroll 1
    for (int row = 0; row < ROWS_PER_BLK; ++row) {
        const int i = i0 + row;

        // ---- features for pair (i, j=p): proven math, 2 threads/pair ----
        {
            const float* qp = q + ((size_t)b * NQ + i) * DIN;
            const float q0 = qp[0], q3 = qp[3], q4 = qp[4], q5 = qp[5],
                        q6 = qp[6], q7 = qp[7], q8 = qp[8];

            const float dpx = k3 - q3, dpy = k4 - q4;
            const float dvx = k5 - q5, dvy = k6 - q6;
            const float dist = sqtf(dpx * dpx + dpy * dpy + 1e-6f);

            float feat[32];
            if (half == 0) {
                // c8 {0,1,6,7}: dist4 | inv_dist4 | ttca2+dist2 | team2+dspeed2
                const float inv_dist = rcpf(dist + 0.1f);
                const float dot_dp_dv = dpx * dvx + dpy * dvy;
                const float speed_sq = dvx * dvx + dvy * dvy;
                // tanh(relu(z)) = 1 - 2/(1 + 2^(2*log2e*z)), z >= 0
                const float z = fmaxf(0.f, -dot_dp_dv * rcpf(speed_sq + 1e-6f));
                const float ttca = 1.f - 2.f * rcpf(1.f + ex2f(2.88539008f * z));
                const float q_speed = sqtf(q5 * q5 + q6 * q6);
                const float delta_speed = k_speed - q_speed;
                four4(dist,     feat + 0);
                four4(inv_dist, feat + 8);
                four2(ttca,     feat + 16);
                feat[20] = feat[0]; feat[21] = feat[1];   // four2(dist) reuse
                feat[22] = feat[4]; feat[23] = feat[5];
                const bool st = (q0 == k0);               // same_team constants
                feat[24] = st ? 0.84147098f : 0.f;
                feat[25] = st ? 0.90929743f : 0.f;
                feat[26] = st ? 0.54030231f : 1.f;
                feat[27] = st ? -0.41614684f : 1.f;
                four2(delta_speed, feat + 28);
            } else {
                // c8 {2,3,4,5}: ata4 | aspect4 | dpx2+dpy2 | dvx2+dvy2
                const float inv_d2 = rcpf(dist + 1e-6f);
                const float bear_x = dpx * inv_d2, bear_y = dpy * inv_d2;
                const float ata = bear_x * q7 + bear_y * q8;
                const float aspect = bear_x * k7 + bear_y * k8;
                four4(ata,    feat + 0);
                four4(aspect, feat + 8);
                four2(dpx,    feat + 16);
                four2(dpy,    feat + 20);
                four2(dvx,    feat + 24);
                four2(dvy,    feat + 28);
            }
#pragma unroll
            for (int j = 0; j < 4; ++j) {
                const int c8 = half ? (j + 2) : (j < 2 ? j : j + 4);
                uint4 v;
                v.x = cvtpk(feat[j * 8 + 0], feat[j * 8 + 1]);
                v.y = cvtpk(feat[j * 8 + 2], feat[j * 8 + 3]);
                v.z = cvtpk(feat[j * 8 + 4], feat[j * 8 + 5]);
                v.w = cvtpk(feat[j * 8 + 6], feat[j * 8 + 7]);
                *(uint4*)&feat_s[p * FSTRIDE + ((c8 ^ sw) * 8)] = v;
            }
        }
        __syncthreads();  // feat_s(row) ready

        // ---- 4 chunks of 64 pairs ----
#pragma unroll 1
        for (int c = 0; c < 4; ++c) {
            const int p0 = c * 64;

            // GEMM1': bias rides as C-in on the ks=0 MFMAs
            f32x4 acc[2][4];
#pragma unroll
            for (int mt = 0; mt < 4; ++mt) {
                const int r2 = p0 + mt * 16 + lane15;
                const bf16x8 fb = *(const bf16x8*)
                    &feat_s[r2 * FSTRIDE + ((quad ^ swr) * 8)];
                acc[0][mt] = __builtin_amdgcn_mfma_f32_16x16x32_bf16(
                    w1f[0][0], fb, b1c[0], 0, 0, 0);
                acc[1][mt] = __builtin_amdgcn_mfma_f32_16x16x32_bf16(
                    w1f[1][0], fb, b1c[1], 0, 0, 0);
            }
#pragma unroll
            for (int mt = 0; mt < 4; ++mt) {
                const int r2 = p0 + mt * 16 + lane15;
                const bf16x8 fb = *(const bf16x8*)
                    &feat_s[r2 * FSTRIDE + (((4 + quad) ^ swr) * 8)];
#pragma unroll
                for (int nt = 0; nt < 2; ++nt)
                    acc[nt][mt] = __builtin_amdgcn_mfma_f32_16x16x32_bf16(
                        w1f[nt][1], fb, acc[nt][mt], 0, 0, 0);
            }

            // silu-COMPUTE into regs (no LDS): packed-f32 add/mul
            uint2 pk[2][4];
#pragma unroll
            for (int nt = 0; nt < 2; ++nt)
#pragma unroll
                for (int mt = 0; mt < 4; ++mt) {
                    const f32x4 a = acc[nt][mt];     // = -log2e * preact
                    const f32x2 a01 = {a[0], a[1]}, a23 = {a[2], a[3]};
                    const f32x2 e01 = {ex2f(a[0]), ex2f(a[1])};
                    const f32x2 e23 = {ex2f(a[2]), ex2f(a[3])};
                    const f32x2 t01 = e01 + one2;    // v_pk_add_f32
                    const f32x2 t23 = e23 + one2;
                    const f32x2 r01 = {rcpf(t01[0]), rcpf(t01[1])};
                    const f32x2 r23 = {rcpf(t23[0]), rcpf(t23[1])};
                    const f32x2 s01 = a01 * r01;     // v_pk_mul_f32
                    const f32x2 s23 = a23 * r23;     // = -1.4427*silu
                    pk[nt][mt].x = cvtpk(s01[0], s01[1]);
                    pk[nt][mt].y = cvtpk(s23[0], s23[1]);
                }

            __syncthreads();  // barrier#1: h_s(prev) fully consumed

            // only the 8 ds_write_b64 live between the barriers
#pragma unroll
            for (int nt = 0; nt < 2; ++nt)
#pragma unroll
                for (int mt = 0; mt < 4; ++mt) {
                    const int pair = mt * 16 + lane15;
                    const int hbase = n0 + nt * 16 + quad * 4;
                    *(uint2*)&h_s[pair * HSTRIDE + hbase] = pk[nt][mt];
                }
            __syncthreads();  // barrier#2: h_s(c) ready

            // GEMM2: waves 0-3, one 16-pair M-tile each; K=256; W2 in regs
            if (wave < 4) {
                const int pw = wave * 16;
                f32x4 acc2 = (f32x4){b2v, b2v, b2v, b2v};
#pragma unroll
                for (int ks = 0; ks < 8; ++ks) {
                    const bf16x8 ha = *(const bf16x8*)&h_s[(pw + lane15) * HSTRIDE
                                                            + ks * 32 + quad * 8];
                    acc2 = __builtin_amdgcn_mfma_f32_16x16x32_bf16(ha, w2f[ks], acc2, 0, 0, 0);
                }
                if (lane15 < NH) {
                    float* op = outp + (size_t)i * NK + p0;
                    *(float4*)op = make_float4(acc2[0], acc2[1], acc2[2], acc2[3]);
                }
            }
            // no end barrier: next chunk's GEMM1' touches only feat_s
        }
    }
}

extern "C" void kernel_launch(void* const* d_in, const int* in_sizes, int n_in,
                              void* d_out, int out_size, void* d_ws, size_t ws_size,
                              hipStream_t stream) {
    const float* q  = (const float*)d_in[0];
    const float* k  = (const float*)d_in[1];
    const float* W1 = (const float*)d_in[2];
    const float* b1 = (const float*)d_in[3];
    const float* W2 = (const float*)d_in[4];
    const float* b2 = (const float*)d_in[5];
    float* out = (float*)d_out;

    dim3 grid(NB * NQ / ROWS_PER_BLK);  // 512 blocks = 2/CU, one dispatch round
    dim3 block(512);                    // 8 waves: 16 waves/CU resident
    relfeat_mfma_kernel<<<grid, block, 0, stream>>>(q, k, W1, b1, W2, b2, out);
}